// Round 6
// baseline (833.726 us; speedup 1.0000x reference)
//
#include <hip/hip_runtime.h>
#include <hip/hip_bf16.h>

#define NN 100000
#define NE 800000
// D=128, H=4, C=32

typedef __attribute__((ext_vector_type(8))) short bf16x8;
typedef __attribute__((ext_vector_type(4))) float f32x4;
typedef unsigned short ushort_t;

static __device__ __forceinline__ short f2bf(float f) {
    union { float f; unsigned u; } v; v.f = f;
    unsigned u = v.u;
    unsigned r = u + 0x7FFFu + ((u >> 16) & 1u);   // RNE
    return (short)(r >> 16);
}
static __device__ __forceinline__ float bf2f(unsigned short u) {
    union { unsigned u; float f; } v; v.u = ((unsigned)u) << 16;
    return v.f;
}

// ---------------- weight prep: W[k][c] fp32 -> Wt[c][k] bf16, 9 matrices ------------
__global__ void prep_w_k(const float* __restrict__ w_in, const float* __restrict__ Wl,
                         const float* __restrict__ Wr, const float* __restrict__ Wres,
                         ushort_t* __restrict__ wt)
{
    __shared__ float tile[32][33];
    int m = blockIdx.z;
    const float* src;
    if (m == 0)      src = w_in;
    else if (m < 4)  src = Wl + (size_t)(m - 1) * 16384;
    else if (m < 7)  src = Wr + (size_t)(m - 4) * 16384;
    else             src = Wres + (size_t)(m - 7) * 16384;
    ushort_t* dst = wt + (size_t)m * 16384;

    int tx = threadIdx.x, ty = threadIdx.y;
    int k0 = blockIdx.x * 32, c0 = blockIdx.y * 32;
    #pragma unroll
    for (int j = 0; j < 4; ++j)
        tile[ty + 8 * j][tx] = src[(size_t)(k0 + ty + 8 * j) * 128 + c0 + tx];
    __syncthreads();
    #pragma unroll
    for (int j = 0; j < 4; ++j)
        dst[(size_t)(c0 + ty + 8 * j) * 128 + k0 + tx] = (ushort_t)f2bf(tile[tx][ty + 8 * j]);
}

// ---------------- GEMM: 64-row tiles, one matrix per block ----------------
// out = A[M x 128] @ wt[w_y]^T + bias. Fragments direct from global.
// blockIdx.y: 0 -> wt[w0] (+bias0) into out0 cols [0,128)
//             1 -> wt[w1] (no bias) into out0 cols [128,256)
//             2 -> wt[w2] (+bias2) into out2 (Dout=128)
template<int A_FP32>
__global__ __launch_bounds__(256, 4)
void gemm_k(const void* __restrict__ Av, const ushort_t* __restrict__ wt,
            int w0, int w1, int w2,
            const float* __restrict__ bias0, const float* __restrict__ bias2,
            ushort_t* __restrict__ out0, int Dout0, ushort_t* __restrict__ out2, int M)
{
    __shared__ short Ct[64][136];    // epilogue C-tile
    const int tid = threadIdx.x;
    const int rowBlk = blockIdx.x * 64;
    const int y = blockIdx.y;
    const ushort_t* W = wt + (size_t)((y == 0) ? w0 : (y == 1) ? w1 : w2) * 16384;
    const float* bias = (y == 0) ? bias0 : ((y == 2) ? bias2 : nullptr);
    ushort_t* out = (y == 2) ? out2 : out0;
    const int Dout   = (y == 2) ? 128 : Dout0;
    const int colOff = (y == 1) ? 128 : 0;

    const int wave = tid >> 6;
    const int lane = tid & 63;
    const int quad = lane >> 4;
    const int lr   = lane & 15;

    const int row = rowBlk + wave * 16 + lr;        // A fragment row (one m-tile/wave)

    // A fragments (read once)
    bf16x8 afr[4];
    #pragma unroll
    for (int ks = 0; ks < 4; ++ks) {
        int kb = ks * 32 + quad * 8;
        bf16x8 a = (bf16x8)0;
        if (A_FP32) {
            const float* A = (const float*)Av;
            if (row < M) {
                float4 v0 = *(const float4*)(A + (size_t)row * 128 + kb);
                float4 v1 = *(const float4*)(A + (size_t)row * 128 + kb + 4);
                a[0]=f2bf(v0.x); a[1]=f2bf(v0.y); a[2]=f2bf(v0.z); a[3]=f2bf(v0.w);
                a[4]=f2bf(v1.x); a[5]=f2bf(v1.y); a[6]=f2bf(v1.z); a[7]=f2bf(v1.w);
            }
        } else {
            const ushort_t* A = (const ushort_t*)Av;
            if (row < M) a = *(const bf16x8*)(A + (size_t)row * 128 + kb);
        }
        afr[ks] = a;
    }

    f32x4 acc[8];
    #pragma unroll
    for (int nt = 0; nt < 8; ++nt) acc[nt] = (f32x4)(0.0f);

    #pragma unroll
    for (int ks = 0; ks < 4; ++ks) {
        int kb = ks * 32 + quad * 8;
        #pragma unroll
        for (int nt = 0; nt < 8; ++nt) {
            bf16x8 b = *(const bf16x8*)(W + (size_t)(nt * 16 + lr) * 128 + kb);
            acc[nt] = __builtin_amdgcn_mfma_f32_16x16x32_bf16(afr[ks], b, acc[nt], 0, 0, 0);
        }
    }

    // epilogue: C/D layout col = lane&15, row = quad*4 + reg
    #pragma unroll
    for (int nt = 0; nt < 8; ++nt) {
        int col = nt * 16 + lr;
        float b = bias ? bias[col] : 0.0f;
        #pragma unroll
        for (int r = 0; r < 4; ++r)
            Ct[wave * 16 + quad * 4 + r][col] = f2bf(acc[nt][r] + b);
    }
    __syncthreads();
    #pragma unroll
    for (int i = 0; i < 4; ++i) {
        int linear = tid + 256 * i;              // 1024 16B chunks
        int r  = linear >> 4;
        int c8 = (linear & 15) << 3;
        int gr = rowBlk + r;
        if (gr < M)
            *(bf16x8*)(out + (size_t)gr * Dout + colOff + c8) = *(const bf16x8*)&Ct[r][c8];
    }
}

// ---------------- CSR build ----------------
__global__ void count_k(const int* __restrict__ dst, int* __restrict__ deg) {
    int e = blockIdx.x * 256 + threadIdx.x;
    if (e < NE) atomicAdd(&deg[dst[e]], 1);
}

__global__ void scan1_k(const int* __restrict__ deg, int* __restrict__ excl,
                        int* __restrict__ bsum) {
    __shared__ int buf[256];
    int i = blockIdx.x * 256 + threadIdx.x;
    int v = (i < NN) ? deg[i] : 0;
    buf[threadIdx.x] = v; __syncthreads();
    for (int off = 1; off < 256; off <<= 1) {
        int t = (threadIdx.x >= off) ? buf[threadIdx.x - off] : 0;
        __syncthreads();
        buf[threadIdx.x] += t;
        __syncthreads();
    }
    if (i < NN) excl[i] = buf[threadIdx.x] - v;
    if (threadIdx.x == 255) bsum[blockIdx.x] = buf[255];
}

__global__ void scan2_k(int* __restrict__ bsum, int nb, int* __restrict__ total) {
    __shared__ int buf[512];
    int v = (threadIdx.x < nb) ? bsum[threadIdx.x] : 0;
    buf[threadIdx.x] = v; __syncthreads();
    for (int off = 1; off < 512; off <<= 1) {
        int t = (threadIdx.x >= off) ? buf[threadIdx.x - off] : 0;
        __syncthreads();
        buf[threadIdx.x] += t;
        __syncthreads();
    }
    if (threadIdx.x < nb) bsum[threadIdx.x] = buf[threadIdx.x] - v;  // exclusive base
    if (threadIdx.x == 511) *total = buf[511];
}

__global__ void scan3_k(int* __restrict__ row_ptr, const int* __restrict__ bsum,
                        int* __restrict__ cursor) {
    int i = blockIdx.x * 256 + threadIdx.x;
    if (i < NN) {
        int v = row_ptr[i] + bsum[blockIdx.x];
        row_ptr[i] = v;
        cursor[i]  = v;
    }
}

__global__ void scatter_k(const int* __restrict__ src, const int* __restrict__ dst,
                          int* __restrict__ cursor, int* __restrict__ csr_src) {
    int e = blockIdx.x * 256 + threadIdx.x;
    if (e < NE) {
        int p = atomicAdd(&cursor[dst[e]], 1);
        csr_src[p] = src[e];
    }
}

// ---------------- GATv2 aggregate: one wave per destination node, 8 edges/iter --------
// xlr bf16 [N][256]: cols 0..127 = xl, cols 128..255 = xr.
// slot = lane>>4 (4 edge slots), 16-lane group covers 128 ch (8 ch/lane, 16B loads).
// 2x manual unroll -> 8 independent gathers in flight per wave.
__global__ __launch_bounds__(256, 8)
void gat_aggregate_k(const ushort_t* __restrict__ xlr, const int* __restrict__ row_ptr,
                     const int* __restrict__ csr_src, const float* __restrict__ att,
                     const float* __restrict__ b_out, ushort_t* __restrict__ g)
{
    int node = blockIdx.x * 4 + (threadIdx.x >> 6);
    int lane = threadIdx.x & 63;
    int slot = lane >> 4;
    int cl   = (lane & 15) << 3;                 // channels cl..cl+7
    bf16x8 xru = *(const bf16x8*)(xlr + (size_t)node * 256 + 128 + cl);
    float xr[8], at[8];
    #pragma unroll
    for (int j = 0; j < 8; ++j) xr[j] = bf2f((ushort_t)xru[j]);
    float4 at0 = *(const float4*)(att + cl);
    float4 at1 = *(const float4*)(att + cl + 4);
    at[0] = at0.x; at[1] = at0.y; at[2] = at0.z; at[3] = at0.w;
    at[4] = at1.x; at[5] = at1.y; at[6] = at1.z; at[7] = at1.w;

    int e0 = row_ptr[node], e1 = row_ptr[node + 1];
    float acc[8] = {0.f,0.f,0.f,0.f,0.f,0.f,0.f,0.f};
    float suma = 0.f;
    for (int e = e0; e < e1; e += 8) {
        int ea = e + slot, eb = e + 4 + slot;
        bool va = ea < e1, vb = eb < e1;
        int sa = csr_src[va ? ea : e];
        int sb = csr_src[vb ? eb : e];
        bf16x8 xua = *(const bf16x8*)(xlr + (size_t)sa * 256 + cl);
        bf16x8 xub = *(const bf16x8*)(xlr + (size_t)sb * 256 + cl);
        float xa[8], xb[8];
        #pragma unroll
        for (int j = 0; j < 8; ++j) { xa[j] = bf2f((ushort_t)xua[j]); xb[j] = bf2f((ushort_t)xub[j]); }
        float pa = 0.f, pb = 0.f;
        #pragma unroll
        for (int j = 0; j < 8; ++j) {
            float ma = xa[j] + xr[j]; ma = fmaxf(ma, 0.2f * ma);
            float mb = xb[j] + xr[j]; mb = fmaxf(mb, 0.2f * mb);
            pa = fmaf(at[j], ma, pa);
            pb = fmaf(at[j], mb, pb);
        }
        pa += __shfl_xor(pa, 1); pa += __shfl_xor(pa, 2);
        pb += __shfl_xor(pb, 1); pb += __shfl_xor(pb, 2);
        float aa = va ? __expf(pa) : 0.f;
        float ab = vb ? __expf(pb) : 0.f;
        suma += aa + ab;
        #pragma unroll
        for (int j = 0; j < 8; ++j) acc[j] = fmaf(aa, xa[j], fmaf(ab, xb[j], acc[j]));
    }
    // combine the four edge slots
    suma += __shfl_xor(suma, 16); suma += __shfl_xor(suma, 32);
    #pragma unroll
    for (int j = 0; j < 8; ++j) {
        acc[j] += __shfl_xor(acc[j], 16);
        acc[j] += __shfl_xor(acc[j], 32);
    }
    if (slot == 0) {
        float inv = 1.0f / (suma + 1e-16f);
        float4 ob0 = *(const float4*)(b_out + cl);
        float4 ob1 = *(const float4*)(b_out + cl + 4);
        float ob[8] = {ob0.x, ob0.y, ob0.z, ob0.w, ob1.x, ob1.y, ob1.z, ob1.w};
        short r[8];
        #pragma unroll
        for (int j = 0; j < 8; ++j) r[j] = f2bf(fmaf(acc[j], inv, ob[j]));
        *(bf16x8*)(g + (size_t)node * 128 + cl) = *(const bf16x8*)r;
    }
}

// ---------------- PairNorm column sums (bf16 g) ----------------
__global__ void colsum_k(const ushort_t* __restrict__ g, float* __restrict__ colsum) {
    __shared__ float buf[256];
    int c = threadIdx.x & 127;
    int half = threadIdx.x >> 7;
    int r0 = blockIdx.x * 256;
    int rend = min(r0 + 256, NN);
    float s = 0.f;
    for (int r = r0 + half; r < rend; r += 2)
        s += bf2f(g[(size_t)r * 128 + c]);
    buf[threadIdx.x] = s;
    __syncthreads();
    if (threadIdx.x < 128)
        atomicAdd(&colsum[c], buf[threadIdx.x] + buf[threadIdx.x + 128]);
}

// ---------------- fused pairnorm + residual + layernorm (+relu) ----------------
__global__ __launch_bounds__(256, 4)
void finalize_k(const ushort_t* __restrict__ g, const float* __restrict__ colsum,
                const ushort_t* __restrict__ ident, const float* __restrict__ lng,
                const float* __restrict__ lnb, ushort_t* __restrict__ hout_bf,
                float* __restrict__ hout_f32, int is_final)
{
    int node = blockIdx.x * 4 + (threadIdx.x >> 6);
    int lane = threadIdx.x & 63;
    int j0 = lane * 2;
    const float invN = 1.0f / (float)NN;
    const float sqrtN = sqrtf((float)NN);

    ushort2 vu = *(const ushort2*)(g + (size_t)node * 128 + j0);
    float x0 = bf2f(vu.x) - colsum[j0] * invN;
    float x1 = bf2f(vu.y) - colsum[j0 + 1] * invN;
    float ss = x0 * x0 + x1 * x1;
    ss += __shfl_xor(ss, 1);  ss += __shfl_xor(ss, 2);  ss += __shfl_xor(ss, 4);
    ss += __shfl_xor(ss, 8);  ss += __shfl_xor(ss, 16); ss += __shfl_xor(ss, 32);
    float sc = sqrtN / (sqrtf(ss) + 1e-6f);

    ushort2 idu = *(const ushort2*)(ident + (size_t)node * 128 + j0);
    float t0 = x0 * sc + bf2f(idu.x);
    float t1 = x1 * sc + bf2f(idu.y);

    float m = t0 + t1;
    m += __shfl_xor(m, 1);  m += __shfl_xor(m, 2);  m += __shfl_xor(m, 4);
    m += __shfl_xor(m, 8);  m += __shfl_xor(m, 16); m += __shfl_xor(m, 32);
    m *= (1.0f / 128.0f);
    float d0 = t0 - m, d1 = t1 - m;
    float vv = d0 * d0 + d1 * d1;
    vv += __shfl_xor(vv, 1);  vv += __shfl_xor(vv, 2);  vv += __shfl_xor(vv, 4);
    vv += __shfl_xor(vv, 8);  vv += __shfl_xor(vv, 16); vv += __shfl_xor(vv, 32);
    vv *= (1.0f / 128.0f);
    float r = rsqrtf(vv + 1e-5f);

    float y0 = d0 * r * lng[j0]     + lnb[j0];
    float y1 = d1 * r * lng[j0 + 1] + lnb[j0 + 1];
    if (is_final) {
        float2 o; o.x = y0; o.y = y1;
        *(float2*)(hout_f32 + (size_t)node * 128 + j0) = o;
    } else {
        y0 = fmaxf(y0, 0.f); y1 = fmaxf(y1, 0.f);
        ushort2 o; o.x = (ushort_t)f2bf(y0); o.y = (ushort_t)f2bf(y1);
        *(ushort2*)(hout_bf + (size_t)node * 128 + j0) = o;
    }
}

// ---------------- host launch ----------------
extern "C" void kernel_launch(void* const* d_in, const int* in_sizes, int n_in,
                              void* d_out, int out_size, void* d_ws, size_t ws_size,
                              hipStream_t stream) {
    const float* x     = (const float*)d_in[0];
    const int*   ei    = (const int*)  d_in[1];   // [2][E]
    const float* w_in  = (const float*)d_in[2];
    const float* b_in  = (const float*)d_in[3];
    const float* Wl    = (const float*)d_in[4];
    const float* bl    = (const float*)d_in[5];
    const float* Wr    = (const float*)d_in[6];
    const float* att   = (const float*)d_in[7];
    const float* b_out = (const float*)d_in[8];
    const float* Wres  = (const float*)d_in[9];
    const float* bres  = (const float*)d_in[10];
    const float* ln_g  = (const float*)d_in[11];
    const float* ln_b  = (const float*)d_in[12];

    // workspace layout (bf16 feature buffers)
    ushort_t* h     = (ushort_t*)d_ws;                 // N*128 bf16
    ushort_t* xlr   = h + (size_t)NN * 128;            // N*256 bf16
    ushort_t* ident = xlr + (size_t)NN * 256;          // N*128 bf16
    ushort_t* g     = ident + (size_t)NN * 128;        // N*128 bf16
    ushort_t* wt    = g + (size_t)NN * 128;            // 9*128*128 bf16 (transposed weights)
    int*   row_ptr = (int*)(wt + 9 * 16384);           // N+1
    int*   cursor  = row_ptr + (NN + 1);               // N     (zeroed; also deg)
    float* colsum  = (float*)(cursor + NN);            // 3*128 (zeroed)
    int*   bsum    = (int*)(colsum + 384);             // 512
    int*   csr_src = bsum + 512;                       // E

    const int* e_src = ei;
    const int* e_dst = ei + NE;

    hipMemsetAsync(cursor, 0, (size_t)(NN + 384) * 4, stream);

    // weight transpose prep (once per call)
    prep_w_k<<<dim3(4, 4, 9), dim3(32, 8), 0, stream>>>(w_in, Wl, Wr, Wres, wt);

    // CSR build
    const int nb = (NN + 255) / 256;             // 391
    count_k  <<<NE / 256, 256, 0, stream>>>(e_dst, cursor);
    scan1_k  <<<nb, 256, 0, stream>>>(cursor, row_ptr, bsum);
    scan2_k  <<<1, 512, 0, stream>>>(bsum, nb, row_ptr + NN);
    scan3_k  <<<nb, 256, 0, stream>>>(row_ptr, bsum, cursor);
    scatter_k<<<NE / 256, 256, 0, stream>>>(e_src, e_dst, cursor, csr_src);

    const int gx = (NN + 63) / 64;               // 1563

    // h = bf16(x @ w_in + b_in)
    gemm_k<1><<<dim3(gx, 1), 256, 0, stream>>>(x, wt, 0, 0, 0,
                                               b_in, nullptr, h, 128, nullptr, NN);

    for (int i = 0; i < 3; ++i) {
        // xlr = bf16(h @ [Wl | Wr] + [bl | 0]); (i>0) ident = bf16(h @ Wres + bres)
        gemm_k<0><<<dim3(gx, (i > 0) ? 3 : 2), 256, 0, stream>>>(
            h, wt, 1 + i, 4 + i, 7 + (i - 1),
            bl + i * 128, (i > 0) ? (bres + (i - 1) * 128) : nullptr,
            xlr, 256, ident, NN);
        gat_aggregate_k<<<NN / 4, 256, 0, stream>>>(xlr, row_ptr, csr_src,
                                                    att + i * 128, b_out + i * 128, g);
        colsum_k<<<nb, 256, 0, stream>>>(g, colsum + i * 128);
        finalize_k<<<NN / 4, 256, 0, stream>>>(g, colsum + i * 128,
                                               (i == 0) ? h : ident,
                                               ln_g + i * 128, ln_b + i * 128,
                                               h, (float*)d_out, (i == 2) ? 1 : 0);
    }
}

// Round 7
// 648.626 us; speedup vs baseline: 1.2854x; 1.2854x over previous
//
#include <hip/hip_runtime.h>
#include <hip/hip_bf16.h>

#define NN 100000
#define NE 800000
// D=128, H=4, C=32

typedef __attribute__((ext_vector_type(8))) short bf16x8;
typedef __attribute__((ext_vector_type(4))) float f32x4;
typedef unsigned short ushort_t;

static __device__ __forceinline__ short f2bf(float f) {
    union { float f; unsigned u; } v; v.f = f;
    unsigned u = v.u;
    unsigned r = u + 0x7FFFu + ((u >> 16) & 1u);   // RNE
    return (short)(r >> 16);
}
static __device__ __forceinline__ float bf2f(unsigned short u) {
    union { unsigned u; float f; } v; v.u = ((unsigned)u) << 16;
    return v.f;
}

// ---------------- weight prep: W[k][c] fp32 -> Wt[c][k] bf16, 9 matrices ------------
__global__ void prep_w_k(const float* __restrict__ w_in, const float* __restrict__ Wl,
                         const float* __restrict__ Wr, const float* __restrict__ Wres,
                         ushort_t* __restrict__ wt)
{
    __shared__ float tile[32][33];
    int m = blockIdx.z;
    const float* src;
    if (m == 0)      src = w_in;
    else if (m < 4)  src = Wl + (size_t)(m - 1) * 16384;
    else if (m < 7)  src = Wr + (size_t)(m - 4) * 16384;
    else             src = Wres + (size_t)(m - 7) * 16384;
    ushort_t* dst = wt + (size_t)m * 16384;

    int tx = threadIdx.x, ty = threadIdx.y;
    int k0 = blockIdx.x * 32, c0 = blockIdx.y * 32;
    #pragma unroll
    for (int j = 0; j < 4; ++j)
        tile[ty + 8 * j][tx] = src[(size_t)(k0 + ty + 8 * j) * 128 + c0 + tx];
    __syncthreads();
    #pragma unroll
    for (int j = 0; j < 4; ++j)
        dst[(size_t)(c0 + ty + 8 * j) * 128 + k0 + tx] = (ushort_t)f2bf(tile[tx][ty + 8 * j]);
}

// ---------------- GEMM: 128-row tiles, B-tile staged dense in LDS ----------------
// out = A[M x 128] @ wt[w_y]^T + bias. A fragments direct from global;
// B staged densely (pre-transposed wt -> straight copy, no bank conflicts);
// LDS tile reused for the C epilogue.
// blockIdx.y: 0 -> wt[w0] (+bias0) into out0 cols [0,128)
//             1 -> wt[w1] (no bias) into out0 cols [128,256)
//             2 -> wt[w2] (+bias2) into out2 (Dout=128)
template<int A_FP32>
__global__ __launch_bounds__(256, 4)
void gemm_k(const void* __restrict__ Av, const ushort_t* __restrict__ wt,
            int w0, int w1, int w2,
            const float* __restrict__ bias0, const float* __restrict__ bias2,
            ushort_t* __restrict__ out0, int Dout0, ushort_t* __restrict__ out2, int M)
{
    __shared__ short Bs[128][136];   // B-tile [col][k]; reused as C-tile [row][col]
    const int tid = threadIdx.x;
    const int rowBlk = blockIdx.x * 128;
    const int y = blockIdx.y;
    const ushort_t* W = wt + (size_t)((y == 0) ? w0 : (y == 1) ? w1 : w2) * 16384;
    const float* bias = (y == 0) ? bias0 : ((y == 2) ? bias2 : nullptr);
    ushort_t* out = (y == 2) ? out2 : out0;
    const int Dout   = (y == 2) ? 128 : Dout0;
    const int colOff = (y == 1) ? 128 : 0;

    const int wave = tid >> 6;
    const int lane = tid & 63;
    const int quad = lane >> 4;
    const int lr   = lane & 15;

    const int row0 = rowBlk + wave * 32 + lr;       // A fragment rows
    const int row1 = row0 + 16;

    // ---- A fragments direct from global (issued first, latency-hidden) ----
    bf16x8 afr[4][2];
    #pragma unroll
    for (int ks = 0; ks < 4; ++ks) {
        int kb = ks * 32 + quad * 8;
        bf16x8 a0 = (bf16x8)0, a1 = (bf16x8)0;
        if (A_FP32) {
            const float* A = (const float*)Av;
            if (row0 < M) {
                float4 v0 = *(const float4*)(A + (size_t)row0 * 128 + kb);
                float4 v1 = *(const float4*)(A + (size_t)row0 * 128 + kb + 4);
                a0[0]=f2bf(v0.x); a0[1]=f2bf(v0.y); a0[2]=f2bf(v0.z); a0[3]=f2bf(v0.w);
                a0[4]=f2bf(v1.x); a0[5]=f2bf(v1.y); a0[6]=f2bf(v1.z); a0[7]=f2bf(v1.w);
            }
            if (row1 < M) {
                float4 v0 = *(const float4*)(A + (size_t)row1 * 128 + kb);
                float4 v1 = *(const float4*)(A + (size_t)row1 * 128 + kb + 4);
                a1[0]=f2bf(v0.x); a1[1]=f2bf(v0.y); a1[2]=f2bf(v0.z); a1[3]=f2bf(v0.w);
                a1[4]=f2bf(v1.x); a1[5]=f2bf(v1.y); a1[6]=f2bf(v1.z); a1[7]=f2bf(v1.w);
            }
        } else {
            const ushort_t* A = (const ushort_t*)Av;
            if (row0 < M) a0 = *(const bf16x8*)(A + (size_t)row0 * 128 + kb);
            if (row1 < M) a1 = *(const bf16x8*)(A + (size_t)row1 * 128 + kb);
        }
        afr[ks][0] = a0; afr[ks][1] = a1;
    }

    // ---- stage B-tile densely: global 16B/lane contiguous -> LDS rows ----
    #pragma unroll
    for (int i = 0; i < 8; ++i) {
        int linear = tid + 256 * i;              // 2048 16B chunks
        int r  = linear >> 4;
        int c8 = (linear & 15) << 3;
        *(bf16x8*)&Bs[r][c8] = *(const bf16x8*)(W + (size_t)r * 128 + c8);
    }
    __syncthreads();

    f32x4 acc[2][8];
    #pragma unroll
    for (int mt = 0; mt < 2; ++mt)
        #pragma unroll
        for (int nt = 0; nt < 8; ++nt) acc[mt][nt] = (f32x4)(0.0f);

    #pragma unroll
    for (int ks = 0; ks < 4; ++ks) {
        int kb = ks * 32 + quad * 8;
        #pragma unroll
        for (int nt = 0; nt < 8; ++nt) {
            bf16x8 b = *(const bf16x8*)&Bs[nt * 16 + lr][kb];
            acc[0][nt] = __builtin_amdgcn_mfma_f32_16x16x32_bf16(afr[ks][0], b, acc[0][nt], 0, 0, 0);
            acc[1][nt] = __builtin_amdgcn_mfma_f32_16x16x32_bf16(afr[ks][1], b, acc[1][nt], 0, 0, 0);
        }
    }

    // ---- epilogue: reuse Bs as C-tile; C/D layout col = lane&15, row = quad*4 + reg
    __syncthreads();                             // all waves done reading B
    #pragma unroll
    for (int mt = 0; mt < 2; ++mt)
        #pragma unroll
        for (int nt = 0; nt < 8; ++nt) {
            int col = nt * 16 + lr;
            float b = bias ? bias[col] : 0.0f;
            #pragma unroll
            for (int r = 0; r < 4; ++r) {
                int row = wave * 32 + mt * 16 + quad * 4 + r;
                Bs[row][col] = f2bf(acc[mt][nt][r] + b);
            }
        }
    __syncthreads();
    #pragma unroll
    for (int i = 0; i < 8; ++i) {
        int linear = tid + 256 * i;              // 2048 16B chunks
        int r  = linear >> 4;
        int c8 = (linear & 15) << 3;
        int gr = rowBlk + r;
        if (gr < M)
            *(bf16x8*)(out + (size_t)gr * Dout + colOff + c8) = *(const bf16x8*)&Bs[r][c8];
    }
}

// ---------------- CSR build ----------------
__global__ void count_k(const int* __restrict__ dst, int* __restrict__ deg) {
    int e = blockIdx.x * 256 + threadIdx.x;
    if (e < NE) atomicAdd(&deg[dst[e]], 1);
}

__global__ void scan1_k(const int* __restrict__ deg, int* __restrict__ excl,
                        int* __restrict__ bsum) {
    __shared__ int buf[256];
    int i = blockIdx.x * 256 + threadIdx.x;
    int v = (i < NN) ? deg[i] : 0;
    buf[threadIdx.x] = v; __syncthreads();
    for (int off = 1; off < 256; off <<= 1) {
        int t = (threadIdx.x >= off) ? buf[threadIdx.x - off] : 0;
        __syncthreads();
        buf[threadIdx.x] += t;
        __syncthreads();
    }
    if (i < NN) excl[i] = buf[threadIdx.x] - v;
    if (threadIdx.x == 255) bsum[blockIdx.x] = buf[255];
}

__global__ void scan2_k(int* __restrict__ bsum, int nb, int* __restrict__ total) {
    __shared__ int buf[512];
    int v = (threadIdx.x < nb) ? bsum[threadIdx.x] : 0;
    buf[threadIdx.x] = v; __syncthreads();
    for (int off = 1; off < 512; off <<= 1) {
        int t = (threadIdx.x >= off) ? buf[threadIdx.x - off] : 0;
        __syncthreads();
        buf[threadIdx.x] += t;
        __syncthreads();
    }
    if (threadIdx.x < nb) bsum[threadIdx.x] = buf[threadIdx.x] - v;  // exclusive base
    if (threadIdx.x == 511) *total = buf[511];
}

__global__ void scan3_k(int* __restrict__ row_ptr, const int* __restrict__ bsum,
                        int* __restrict__ cursor) {
    int i = blockIdx.x * 256 + threadIdx.x;
    if (i < NN) {
        int v = row_ptr[i] + bsum[blockIdx.x];
        row_ptr[i] = v;
        cursor[i]  = v;
    }
}

__global__ void scatter_k(const int* __restrict__ src, const int* __restrict__ dst,
                          int* __restrict__ cursor, int* __restrict__ csr_src) {
    int e = blockIdx.x * 256 + threadIdx.x;
    if (e < NE) {
        int p = atomicAdd(&cursor[dst[e]], 1);
        csr_src[p] = src[e];
    }
}

// ---------------- GATv2 aggregate: one wave per destination node, 8 edges/iter --------
__global__ __launch_bounds__(256, 8)
void gat_aggregate_k(const ushort_t* __restrict__ xlr, const int* __restrict__ row_ptr,
                     const int* __restrict__ csr_src, const float* __restrict__ att,
                     const float* __restrict__ b_out, ushort_t* __restrict__ g)
{
    int node = blockIdx.x * 4 + (threadIdx.x >> 6);
    int lane = threadIdx.x & 63;
    int slot = lane >> 4;
    int cl   = (lane & 15) << 3;                 // channels cl..cl+7
    bf16x8 xru = *(const bf16x8*)(xlr + (size_t)node * 256 + 128 + cl);
    float xr[8], at[8];
    #pragma unroll
    for (int j = 0; j < 8; ++j) xr[j] = bf2f((ushort_t)xru[j]);
    float4 at0 = *(const float4*)(att + cl);
    float4 at1 = *(const float4*)(att + cl + 4);
    at[0] = at0.x; at[1] = at0.y; at[2] = at0.z; at[3] = at0.w;
    at[4] = at1.x; at[5] = at1.y; at[6] = at1.z; at[7] = at1.w;

    int e0 = row_ptr[node], e1 = row_ptr[node + 1];
    float acc[8] = {0.f,0.f,0.f,0.f,0.f,0.f,0.f,0.f};
    float suma = 0.f;
    for (int e = e0; e < e1; e += 8) {
        int ea = e + slot, eb = e + 4 + slot;
        bool va = ea < e1, vb = eb < e1;
        int sa = csr_src[va ? ea : e];
        int sb = csr_src[vb ? eb : e];
        bf16x8 xua = *(const bf16x8*)(xlr + (size_t)sa * 256 + cl);
        bf16x8 xub = *(const bf16x8*)(xlr + (size_t)sb * 256 + cl);
        float xa[8], xb[8];
        #pragma unroll
        for (int j = 0; j < 8; ++j) { xa[j] = bf2f((ushort_t)xua[j]); xb[j] = bf2f((ushort_t)xub[j]); }
        float pa = 0.f, pb = 0.f;
        #pragma unroll
        for (int j = 0; j < 8; ++j) {
            float ma = xa[j] + xr[j]; ma = fmaxf(ma, 0.2f * ma);
            float mb = xb[j] + xr[j]; mb = fmaxf(mb, 0.2f * mb);
            pa = fmaf(at[j], ma, pa);
            pb = fmaf(at[j], mb, pb);
        }
        pa += __shfl_xor(pa, 1); pa += __shfl_xor(pa, 2);
        pb += __shfl_xor(pb, 1); pb += __shfl_xor(pb, 2);
        float aa = va ? __expf(pa) : 0.f;
        float ab = vb ? __expf(pb) : 0.f;
        suma += aa + ab;
        #pragma unroll
        for (int j = 0; j < 8; ++j) acc[j] = fmaf(aa, xa[j], fmaf(ab, xb[j], acc[j]));
    }
    // combine the four edge slots
    suma += __shfl_xor(suma, 16); suma += __shfl_xor(suma, 32);
    #pragma unroll
    for (int j = 0; j < 8; ++j) {
        acc[j] += __shfl_xor(acc[j], 16);
        acc[j] += __shfl_xor(acc[j], 32);
    }
    if (slot == 0) {
        float inv = 1.0f / (suma + 1e-16f);
        float4 ob0 = *(const float4*)(b_out + cl);
        float4 ob1 = *(const float4*)(b_out + cl + 4);
        float ob[8] = {ob0.x, ob0.y, ob0.z, ob0.w, ob1.x, ob1.y, ob1.z, ob1.w};
        short r[8];
        #pragma unroll
        for (int j = 0; j < 8; ++j) r[j] = f2bf(fmaf(acc[j], inv, ob[j]));
        *(bf16x8*)(g + (size_t)node * 128 + cl) = *(const bf16x8*)r;
    }
}

// ---------------- PairNorm column sums (bf16 g) ----------------
__global__ void colsum_k(const ushort_t* __restrict__ g, float* __restrict__ colsum) {
    __shared__ float buf[256];
    int c = threadIdx.x & 127;
    int half = threadIdx.x >> 7;
    int r0 = blockIdx.x * 256;
    int rend = min(r0 + 256, NN);
    float s = 0.f;
    for (int r = r0 + half; r < rend; r += 2)
        s += bf2f(g[(size_t)r * 128 + c]);
    buf[threadIdx.x] = s;
    __syncthreads();
    if (threadIdx.x < 128)
        atomicAdd(&colsum[c], buf[threadIdx.x] + buf[threadIdx.x + 128]);
}

// ---------------- fused pairnorm + residual + layernorm (+relu) ----------------
__global__ __launch_bounds__(256, 4)
void finalize_k(const ushort_t* __restrict__ g, const float* __restrict__ colsum,
                const ushort_t* __restrict__ ident, const float* __restrict__ lng,
                const float* __restrict__ lnb, ushort_t* __restrict__ hout_bf,
                float* __restrict__ hout_f32, int is_final)
{
    int node = blockIdx.x * 4 + (threadIdx.x >> 6);
    int lane = threadIdx.x & 63;
    int j0 = lane * 2;
    const float invN = 1.0f / (float)NN;
    const float sqrtN = sqrtf((float)NN);

    ushort2 vu = *(const ushort2*)(g + (size_t)node * 128 + j0);
    float x0 = bf2f(vu.x) - colsum[j0] * invN;
    float x1 = bf2f(vu.y) - colsum[j0 + 1] * invN;
    float ss = x0 * x0 + x1 * x1;
    ss += __shfl_xor(ss, 1);  ss += __shfl_xor(ss, 2);  ss += __shfl_xor(ss, 4);
    ss += __shfl_xor(ss, 8);  ss += __shfl_xor(ss, 16); ss += __shfl_xor(ss, 32);
    float sc = sqrtN / (sqrtf(ss) + 1e-6f);

    ushort2 idu = *(const ushort2*)(ident + (size_t)node * 128 + j0);
    float t0 = x0 * sc + bf2f(idu.x);
    float t1 = x1 * sc + bf2f(idu.y);

    float m = t0 + t1;
    m += __shfl_xor(m, 1);  m += __shfl_xor(m, 2);  m += __shfl_xor(m, 4);
    m += __shfl_xor(m, 8);  m += __shfl_xor(m, 16); m += __shfl_xor(m, 32);
    m *= (1.0f / 128.0f);
    float d0 = t0 - m, d1 = t1 - m;
    float vv = d0 * d0 + d1 * d1;
    vv += __shfl_xor(vv, 1);  vv += __shfl_xor(vv, 2);  vv += __shfl_xor(vv, 4);
    vv += __shfl_xor(vv, 8);  vv += __shfl_xor(vv, 16); vv += __shfl_xor(vv, 32);
    vv *= (1.0f / 128.0f);
    float r = rsqrtf(vv + 1e-5f);

    float y0 = d0 * r * lng[j0]     + lnb[j0];
    float y1 = d1 * r * lng[j0 + 1] + lnb[j0 + 1];
    if (is_final) {
        float2 o; o.x = y0; o.y = y1;
        *(float2*)(hout_f32 + (size_t)node * 128 + j0) = o;
    } else {
        y0 = fmaxf(y0, 0.f); y1 = fmaxf(y1, 0.f);
        ushort2 o; o.x = (ushort_t)f2bf(y0); o.y = (ushort_t)f2bf(y1);
        *(ushort2*)(hout_bf + (size_t)node * 128 + j0) = o;
    }
}

// ---------------- host launch ----------------
extern "C" void kernel_launch(void* const* d_in, const int* in_sizes, int n_in,
                              void* d_out, int out_size, void* d_ws, size_t ws_size,
                              hipStream_t stream) {
    const float* x     = (const float*)d_in[0];
    const int*   ei    = (const int*)  d_in[1];   // [2][E]
    const float* w_in  = (const float*)d_in[2];
    const float* b_in  = (const float*)d_in[3];
    const float* Wl    = (const float*)d_in[4];
    const float* bl    = (const float*)d_in[5];
    const float* Wr    = (const float*)d_in[6];
    const float* att   = (const float*)d_in[7];
    const float* b_out = (const float*)d_in[8];
    const float* Wres  = (const float*)d_in[9];
    const float* bres  = (const float*)d_in[10];
    const float* ln_g  = (const float*)d_in[11];
    const float* ln_b  = (const float*)d_in[12];

    // workspace layout (bf16 feature buffers)
    ushort_t* h     = (ushort_t*)d_ws;                 // N*128 bf16
    ushort_t* xlr   = h + (size_t)NN * 128;            // N*256 bf16
    ushort_t* ident = xlr + (size_t)NN * 256;          // N*128 bf16
    ushort_t* g     = ident + (size_t)NN * 128;        // N*128 bf16
    ushort_t* wt    = g + (size_t)NN * 128;            // 9*128*128 bf16 (transposed weights)
    int*   row_ptr = (int*)(wt + 9 * 16384);           // N+1
    int*   cursor  = row_ptr + (NN + 1);               // N     (zeroed; also deg)
    float* colsum  = (float*)(cursor + NN);            // 3*128 (zeroed)
    int*   bsum    = (int*)(colsum + 384);             // 512
    int*   csr_src = bsum + 512;                       // E

    const int* e_src = ei;
    const int* e_dst = ei + NE;

    hipMemsetAsync(cursor, 0, (size_t)(NN + 384) * 4, stream);

    // weight transpose prep (once per call)
    prep_w_k<<<dim3(4, 4, 9), dim3(32, 8), 0, stream>>>(w_in, Wl, Wr, Wres, wt);

    // CSR build
    const int nb = (NN + 255) / 256;             // 391
    count_k  <<<NE / 256, 256, 0, stream>>>(e_dst, cursor);
    scan1_k  <<<nb, 256, 0, stream>>>(cursor, row_ptr, bsum);
    scan2_k  <<<1, 512, 0, stream>>>(bsum, nb, row_ptr + NN);
    scan3_k  <<<nb, 256, 0, stream>>>(row_ptr, bsum, cursor);
    scatter_k<<<NE / 256, 256, 0, stream>>>(e_src, e_dst, cursor, csr_src);

    const int gx = (NN + 127) / 128;             // 782

    // h = bf16(x @ w_in + b_in)
    gemm_k<1><<<dim3(gx, 1), 256, 0, stream>>>(x, wt, 0, 0, 0,
                                               b_in, nullptr, h, 128, nullptr, NN);

    for (int i = 0; i < 3; ++i) {
        // xlr = bf16(h @ [Wl | Wr] + [bl | 0]); (i>0) ident = bf16(h @ Wres + bres)
        gemm_k<0><<<dim3(gx, (i > 0) ? 3 : 2), 256, 0, stream>>>(
            h, wt, 1 + i, 4 + i, 7 + (i - 1),
            bl + i * 128, (i > 0) ? (bres + (i - 1) * 128) : nullptr,
            xlr, 256, ident, NN);
        gat_aggregate_k<<<NN / 4, 256, 0, stream>>>(xlr, row_ptr, csr_src,
                                                    att + i * 128, b_out + i * 128, g);
        colsum_k<<<nb, 256, 0, stream>>>(g, colsum + i * 128);
        finalize_k<<<NN / 4, 256, 0, stream>>>(g, colsum + i * 128,
                                               (i == 0) ? h : ident,
                                               ln_g + i * 128, ln_b + i * 128,
                                               h, (float*)d_out, (i == 2) ? 1 : 0);
    }
}